// Round 3
// baseline (303.730 us; speedup 1.0000x reference)
//
#include <hip/hip_runtime.h>
#include <hip/hip_bf16.h>

// Problem: N=64, C=M=128, F=2048
//   scores[n,c,m] = sum_f X[n,c,f]*A[c,m,f];  W = softmax_m(scores)
//   out[n,c,f]    = sum_m W[n,c,m]*X[n,m,f]
// Round-3 design: NO LDS, NO barriers in either GEMM. All MFMA fragments are
// loaded straight from global memory with per-lane addressing into NAMED
// registers (rule #20: no loop-var-indexed arrays -> no scratch). Double-
// buffered by hand (U/V named structs). __launch_bounds__(256,2): VGPR cap
// 256 guarantees no spill; 2 blocks/CU gives >=24KB of loads in flight/CU
// (> ~9KB BW*latency product), so HBM stays saturated.

typedef __attribute__((ext_vector_type(8))) short bf16x8;
typedef __attribute__((ext_vector_type(4))) float f32x4;

#define PART_ELEMS (64 * 128 * 128)           // one K-partial of scores (fp32), 4 MiB
#define WOFF_BYTES (4ull * PART_ELEMS * 4ull) // 16 MiB of partials, then W bf16 (2 MiB)

static __device__ __forceinline__ unsigned f2bf_pk(float a, float b) {
    unsigned ua = __float_as_uint(a);
    unsigned ub = __float_as_uint(b);
    ua = (ua + 0x7FFFu + ((ua >> 16) & 1u)) >> 16;
    ub = (ub + 0x7FFFu + ((ub >> 16) & 1u)) >> 16;
    return ua | (ub << 16);
}

static __device__ __forceinline__ bf16x8 pack8(float4 x, float4 y) {
    // v_cvt_pk_bf16_f32 path (RNE)
    union { bf16x8 v; __hip_bfloat162 h[4]; } r;
    r.h[0] = __float22bfloat162_rn(make_float2(x.x, x.y));
    r.h[1] = __float22bfloat162_rn(make_float2(x.z, x.w));
    r.h[2] = __float22bfloat162_rn(make_float2(y.x, y.y));
    r.h[3] = __float22bfloat162_rn(make_float2(y.z, y.w));
    return r.v;
}

static __device__ __forceinline__ bf16x8 pack8s(float a0, float a1, float a2, float a3,
                                                float a4, float a5, float a6, float a7) {
    union { bf16x8 v; __hip_bfloat162 h[4]; } r;
    r.h[0] = __float22bfloat162_rn(make_float2(a0, a1));
    r.h[1] = __float22bfloat162_rn(make_float2(a2, a3));
    r.h[2] = __float22bfloat162_rn(make_float2(a4, a5));
    r.h[3] = __float22bfloat162_rn(make_float2(a6, a7));
    return r.v;
}

// ---------------- Kernel 1: partial scores (pure streaming, no LDS) -------
// grid 512 = (c:128) x (K-quarter p:4); block 256 (4 waves).
// Wave (nh = n-half 32, mh = m-half 64). acc[2 nt][4 mt] as 8 named f32x4.
// a-frag(nt): X[nh+nt*16+l15, c, k..k+8]  -> 2 x dwordx4 (row-contiguous)
// b-frag(mt): A[c, mh+mt*16+l15, k..k+8]  -> 2 x dwordx4 (row-contiguous)
__global__ __launch_bounds__(256, 2) void k_scores(const float* __restrict__ X,
                                                   const float* __restrict__ A,
                                                   float* __restrict__ part) {
    constexpr int KW  = 512;        // K window per block
    constexpr int NKS = KW / 32;    // 16 k-steps

    const int bx = blockIdx.x;
    const int c  = bx >> 2;
    const int p  = bx & 3;
    const int t  = threadIdx.x;
    const int l  = t & 63;
    const int w  = t >> 6;
    const int l15 = l & 15;
    const int lg  = l >> 4;
    const int nh = (w & 1) * 32;
    const int mh = (w >> 1) * 64;

    const float* Xb = X + ((size_t)(nh + l15) * 128 + c) * 2048 + p * KW + lg * 8;
    const float* Ab = A + ((size_t)c * 128 + mh + l15) * 2048 + p * KW + lg * 8;

    struct Buf { float4 a0, a1, a2, a3, b0, b1, b2, b3, b4, b5, b6, b7; };

#define SLD(B, ko) do {                                              \
        B.a0 = *(const float4*)(Xb + (ko));                          \
        B.a1 = *(const float4*)(Xb + (ko) + 4);                      \
        B.a2 = *(const float4*)(Xb + 16 * 128 * 2048 + (ko));        \
        B.a3 = *(const float4*)(Xb + 16 * 128 * 2048 + (ko) + 4);    \
        B.b0 = *(const float4*)(Ab + (ko));                          \
        B.b1 = *(const float4*)(Ab + (ko) + 4);                      \
        B.b2 = *(const float4*)(Ab + 16 * 2048 + (ko));              \
        B.b3 = *(const float4*)(Ab + 16 * 2048 + (ko) + 4);          \
        B.b4 = *(const float4*)(Ab + 32 * 2048 + (ko));              \
        B.b5 = *(const float4*)(Ab + 32 * 2048 + (ko) + 4);          \
        B.b6 = *(const float4*)(Ab + 48 * 2048 + (ko));              \
        B.b7 = *(const float4*)(Ab + 48 * 2048 + (ko) + 4);          \
    } while (0)

    f32x4 acc00 = (f32x4)0.f, acc01 = (f32x4)0.f, acc02 = (f32x4)0.f, acc03 = (f32x4)0.f;
    f32x4 acc10 = (f32x4)0.f, acc11 = (f32x4)0.f, acc12 = (f32x4)0.f, acc13 = (f32x4)0.f;

#define SCOMP(B) do {                                                            \
        bf16x8 fa0 = pack8(B.a0, B.a1);                                          \
        bf16x8 fa1 = pack8(B.a2, B.a3);                                          \
        bf16x8 fb0 = pack8(B.b0, B.b1);                                          \
        bf16x8 fb1 = pack8(B.b2, B.b3);                                          \
        bf16x8 fb2 = pack8(B.b4, B.b5);                                          \
        bf16x8 fb3 = pack8(B.b6, B.b7);                                          \
        acc00 = __builtin_amdgcn_mfma_f32_16x16x32_bf16(fa0, fb0, acc00, 0, 0, 0); \
        acc01 = __builtin_amdgcn_mfma_f32_16x16x32_bf16(fa0, fb1, acc01, 0, 0, 0); \
        acc02 = __builtin_amdgcn_mfma_f32_16x16x32_bf16(fa0, fb2, acc02, 0, 0, 0); \
        acc03 = __builtin_amdgcn_mfma_f32_16x16x32_bf16(fa0, fb3, acc03, 0, 0, 0); \
        acc10 = __builtin_amdgcn_mfma_f32_16x16x32_bf16(fa1, fb0, acc10, 0, 0, 0); \
        acc11 = __builtin_amdgcn_mfma_f32_16x16x32_bf16(fa1, fb1, acc11, 0, 0, 0); \
        acc12 = __builtin_amdgcn_mfma_f32_16x16x32_bf16(fa1, fb2, acc12, 0, 0, 0); \
        acc13 = __builtin_amdgcn_mfma_f32_16x16x32_bf16(fa1, fb3, acc13, 0, 0, 0); \
    } while (0)

    Buf U, V;
    SLD(U, 0);
    SLD(V, 32);
#pragma unroll
    for (int kk = 0; kk < NKS; kk += 2) {
        SCOMP(U);
        if (kk + 2 < NKS) SLD(U, (kk + 2) * 32);
        SCOMP(V);
        if (kk + 3 < NKS) SLD(V, (kk + 3) * 32);
    }
#undef SLD
#undef SCOMP

    float* outp = part + (size_t)p * PART_ELEMS + c * 128;
#define SST(av, nt, mt) do {                                                       \
        float* o = outp + (size_t)(nh + (nt) * 16 + lg * 4) * 16384                \
                        + mh + (mt) * 16 + l15;                                    \
        o[0] = av[0]; o[16384] = av[1]; o[32768] = av[2]; o[49152] = av[3];        \
    } while (0)
    SST(acc00, 0, 0); SST(acc01, 0, 1); SST(acc02, 0, 2); SST(acc03, 0, 3);
    SST(acc10, 1, 0); SST(acc11, 1, 1); SST(acc12, 1, 2); SST(acc13, 1, 3);
#undef SST
}

// ---------------- Kernel 2: sum partials + softmax -> W (bf16) -----------
// grid 2048 x 256: one wave per (n,c) row of 128 scores
__global__ __launch_bounds__(256) void k_softmax(const float* __restrict__ part,
                                                 unsigned int* __restrict__ Wout) {
    const int t   = threadIdx.x;
    const int l   = t & 63;
    const int row = blockIdx.x * 4 + (t >> 6);   // row = n*128 + c, < 8192

    const float* s = part + (size_t)row * 128 + 2 * l;
    float v0 = 0.f, v1 = 0.f;
#pragma unroll
    for (int p = 0; p < 4; ++p) {
        float2 v = *(const float2*)(s + (size_t)p * PART_ELEMS);
        v0 += v.x; v1 += v.y;
    }
    float mx = fmaxf(v0, v1);
#pragma unroll
    for (int d = 1; d < 64; d <<= 1) mx = fmaxf(mx, __shfl_xor(mx, d, 64));
    float e0 = __expf(v0 - mx), e1 = __expf(v1 - mx);
    float sm = e0 + e1;
#pragma unroll
    for (int d = 1; d < 64; d <<= 1) sm += __shfl_xor(sm, d, 64);
    const float inv = 1.0f / sm;
    Wout[(size_t)row * 64 + l] = f2bf_pk(e0 * inv, e1 * inv);
}

// ---------------- Kernel 3: combine (pure streaming, no LDS) --------------
// out[n] (128c x 2048f) = W[n] (128x128) @ X[n] (128m x 2048f)
// grid 1024 = (n:64) x (f-tile:16, 128 wide); block 256; wave owns 32 f cols.
// a-frag(i): W[n, i*16+l15, m..m+8] -> already bf16, ONE dwordx4, no pack.
// b-frag(j): X[n, m..m+8, f0+j*16+l15] -> 8 row-strided scalars (4x64B
//            segments per instruction; every X line touched exactly once).
__global__ __launch_bounds__(256, 2) void k_combine(const float* __restrict__ X,
                                                    const unsigned short* __restrict__ W,
                                                    float* __restrict__ out) {
    const int bx = blockIdx.x;
    const int n  = bx >> 4;
    const int t  = threadIdx.x;
    const int l  = t & 63;
    const int w  = t >> 6;
    const int l15 = l & 15;
    const int lg  = l >> 4;
    const int f0 = (bx & 15) * 128 + w * 32;

    // A-operand rows c = i*16 + l15, k = m = ks*32 + lg*8
    const unsigned short* Wb = W + ((size_t)n * 128 + l15) * 128 + lg * 8;
    // B-operand cols f = f0 + j*16 + l15, k = m = ks*32 + lg*8 + r
    const float* Xb = X + ((size_t)n * 128 + lg * 8) * 2048 + f0 + l15;

    struct XBuf { float a0, a1, a2, a3, a4, a5, a6, a7,
                        b0, b1, b2, b3, b4, b5, b6, b7; };

#define CLD(S, ks) do {                                   \
        S.a0 = Xb[((ks) * 32 + 0) * 2048];                \
        S.a1 = Xb[((ks) * 32 + 1) * 2048];                \
        S.a2 = Xb[((ks) * 32 + 2) * 2048];                \
        S.a3 = Xb[((ks) * 32 + 3) * 2048];                \
        S.a4 = Xb[((ks) * 32 + 4) * 2048];                \
        S.a5 = Xb[((ks) * 32 + 5) * 2048];                \
        S.a6 = Xb[((ks) * 32 + 6) * 2048];                \
        S.a7 = Xb[((ks) * 32 + 7) * 2048];                \
        S.b0 = Xb[((ks) * 32 + 0) * 2048 + 16];           \
        S.b1 = Xb[((ks) * 32 + 1) * 2048 + 16];           \
        S.b2 = Xb[((ks) * 32 + 2) * 2048 + 16];           \
        S.b3 = Xb[((ks) * 32 + 3) * 2048 + 16];           \
        S.b4 = Xb[((ks) * 32 + 4) * 2048 + 16];           \
        S.b5 = Xb[((ks) * 32 + 5) * 2048 + 16];           \
        S.b6 = Xb[((ks) * 32 + 6) * 2048 + 16];           \
        S.b7 = Xb[((ks) * 32 + 7) * 2048 + 16];           \
    } while (0)

    f32x4 acc[8][2];
#pragma unroll
    for (int i = 0; i < 8; ++i) {
        acc[i][0] = (f32x4)0.f;
        acc[i][1] = (f32x4)0.f;
    }

#define CCOMP(S, ks) do {                                                          \
        bf16x8 q0 = pack8s(S.a0, S.a1, S.a2, S.a3, S.a4, S.a5, S.a6, S.a7);        \
        bf16x8 q1 = pack8s(S.b0, S.b1, S.b2, S.b3, S.b4, S.b5, S.b6, S.b7);        \
        const unsigned short* wp = Wb + (ks) * 32;                                 \
        _Pragma("unroll")                                                          \
        for (int i = 0; i < 8; ++i) {                                              \
            bf16x8 af = *(const bf16x8*)(wp + (size_t)i * 16 * 128);               \
            acc[i][0] = __builtin_amdgcn_mfma_f32_16x16x32_bf16(af, q0, acc[i][0], 0, 0, 0); \
            acc[i][1] = __builtin_amdgcn_mfma_f32_16x16x32_bf16(af, q1, acc[i][1], 0, 0, 0); \
        }                                                                          \
    } while (0)

    XBuf U, V;
    CLD(U, 0);
    CLD(V, 1);
    CCOMP(U, 0);
    CLD(U, 2);
    CCOMP(V, 1);
    CLD(V, 3);
    CCOMP(U, 2);
    CCOMP(V, 3);
#undef CLD
#undef CCOMP

#pragma unroll
    for (int i = 0; i < 8; ++i) {
#pragma unroll
        for (int j = 0; j < 2; ++j) {
            float* o = out + ((size_t)n * 128 + i * 16 + lg * 4) * 2048 + f0 + j * 16 + l15;
            o[0]        = acc[i][j][0];
            o[2048]     = acc[i][j][1];
            o[2 * 2048] = acc[i][j][2];
            o[3 * 2048] = acc[i][j][3];
        }
    }
}

extern "C" void kernel_launch(void* const* d_in, const int* in_sizes, int n_in,
                              void* d_out, int out_size, void* d_ws, size_t ws_size,
                              hipStream_t stream) {
    const float* X = (const float*)d_in[0];   // [64,128,2048]
    const float* A = (const float*)d_in[1];   // [128,128,2048]
    float* out = (float*)d_out;               // [64,128,2048]

    float* part = (float*)d_ws;                                        // 16 MiB
    unsigned short* W = (unsigned short*)((char*)d_ws + WOFF_BYTES);   // 2 MiB bf16

    k_scores<<<dim3(512), dim3(256), 0, stream>>>(X, A, part);
    k_softmax<<<dim3(2048), dim3(256), 0, stream>>>(part, (unsigned int*)W);
    k_combine<<<dim3(1024), dim3(256), 0, stream>>>(X, W, out);
}

// Round 4
// 279.839 us; speedup vs baseline: 1.0854x; 1.0854x over previous
//
#include <hip/hip_runtime.h>
#include <hip/hip_bf16.h>

// Problem: N=64, C=M=128, F=2048
//   scores[n,c,m] = sum_f X[n,c,f]*A[c,m,f];  W = softmax_m(scores)
//   out[n,c,f]    = sum_m W[n,c,m]*X[n,m,f]
// Round-4: both GEMMs use the proven m97 structure — async global->LDS DMA
// (__builtin_amdgcn_global_load_lds, width 16) with double-buffered LDS and
// one barrier per K-step. In-flight bytes live in the DMA queue, NOT VGPRs,
// so the compiler cannot collapse the pipeline (rounds 1-3 failure mode).
// LDS tiles are row-major; bank conflicts killed via rule-#21 both-sides
// XOR swizzle: linear LDS dest + pre-swizzled GLOBAL source + same XOR on
// the LDS read side.

typedef __attribute__((ext_vector_type(8))) short bf16x8;
typedef __attribute__((ext_vector_type(4))) float f32x4;

#define PART_ELEMS (64 * 128 * 128)           // one K-partial of scores (fp32)
#define WOFF_BYTES (4ull * PART_ELEMS * 4ull) // 16 MiB partials, then W bf16

typedef __attribute__((address_space(3))) void lds_vp;
typedef const __attribute__((address_space(1))) void glob_vp;

static __device__ __forceinline__ void gload_lds16(const void* g, void* l) {
    __builtin_amdgcn_global_load_lds((glob_vp*)g, (lds_vp*)l, 16, 0, 0);
}

static __device__ __forceinline__ unsigned f2bf_pk(float a, float b) {
    unsigned ua = __float_as_uint(a);
    unsigned ub = __float_as_uint(b);
    ua = (ua + 0x7FFFu + ((ua >> 16) & 1u)) >> 16;
    ub = (ub + 0x7FFFu + ((ub >> 16) & 1u)) >> 16;
    return ua | (ub << 16);
}

static __device__ __forceinline__ bf16x8 pack8v(f32x4 x, f32x4 y) {
    union { bf16x8 v; __hip_bfloat162 h[4]; } r;
    r.h[0] = __float22bfloat162_rn(make_float2(x[0], x[1]));
    r.h[1] = __float22bfloat162_rn(make_float2(x[2], x[3]));
    r.h[2] = __float22bfloat162_rn(make_float2(y[0], y[1]));
    r.h[3] = __float22bfloat162_rn(make_float2(y[2], y[3]));
    return r.v;
}

static __device__ __forceinline__ bf16x8 pack8s(float a0, float a1, float a2, float a3,
                                                float a4, float a5, float a6, float a7) {
    union { bf16x8 v; __hip_bfloat162 h[4]; } r;
    r.h[0] = __float22bfloat162_rn(make_float2(a0, a1));
    r.h[1] = __float22bfloat162_rn(make_float2(a2, a3));
    r.h[2] = __float22bfloat162_rn(make_float2(a4, a5));
    r.h[3] = __float22bfloat162_rn(make_float2(a6, a7));
    return r.v;
}

// ---------------- Kernel 1: partial scores (DMA-staged) -------------------
// grid 512 = (c:128) x (K-quarter p:4); block 256 (4 waves); BK=32 floats,
// 16 K-steps. LDS per buffer: X[64][32] (8 KB) + A[128][32] (16 KB) = 24 KB,
// double-buffered 48 KB. 24 global_load_lds dwordx4 per step (6 per wave).
// Swizzle: LDS[row][b] = G[row][b ^ ((row&7)<<4)] for both tiles.
__global__ __launch_bounds__(256, 2) void k_scores(const float* __restrict__ X,
                                                   const float* __restrict__ A,
                                                   float* __restrict__ part) {
    __shared__ float lds[2][6144];   // [buf][ X: 0..2047 | A: 2048..6143 ]

    const int bx = blockIdx.x;
    const int c  = bx >> 2;
    const int p  = bx & 3;
    const int t  = threadIdx.x;
    const int l  = t & 63;
    const int w  = t >> 6;
    const int l15 = l & 15;
    const int lg  = l >> 4;
    const int nh  = (w & 1) * 32;
    const int mh  = (w >> 1) * 64;

    // staging: lane covers 16B of a 128B row; row-within-8 = l>>3
    const int lr   = l >> 3;
    const int sw16 = ((l & 7) ^ lr) << 4;   // pre-swizzled byte-in-row

    const char* xg[2];
#pragma unroll
    for (int q = 0; q < 2; ++q) {
        const int n = w * 16 + q * 8 + lr;   // n&7 == lr
        xg[q] = (const char*)(X + ((size_t)n * 128 + c) * 2048 + p * 512) + sw16;
    }
    const char* ag[4];
#pragma unroll
    for (int q = 0; q < 4; ++q) {
        const int m = w * 32 + q * 8 + lr;   // m&7 == lr
        ag[q] = (const char*)(A + ((size_t)c * 128 + m) * 2048 + p * 512) + sw16;
    }

#define STAGE(d, ks) do {                                                    \
        _Pragma("unroll")                                                    \
        for (int q = 0; q < 2; ++q)                                          \
            gload_lds16(xg[q] + (ks) * 128, &lds[d][(w * 2 + q) * 256]);     \
        _Pragma("unroll")                                                    \
        for (int q = 0; q < 4; ++q)                                          \
            gload_lds16(ag[q] + (ks) * 128, &lds[d][2048 + (w * 4 + q) * 256]); \
    } while (0)

    f32x4 acc[2][4];
#pragma unroll
    for (int i = 0; i < 2; ++i)
#pragma unroll
        for (int j = 0; j < 4; ++j) acc[i][j] = (f32x4)0.0f;

#define SCOMP(d) do {                                                        \
        bf16x8 fa[2], fb[4];                                                 \
        _Pragma("unroll")                                                    \
        for (int i = 0; i < 2; ++i) {                                        \
            const int n = nh + 16 * i + l15;                                 \
            const char* base = (const char*)&lds[d][n * 32];                 \
            const int xo = (n & 7) << 4;                                     \
            f32x4 lo = *(const f32x4*)(base + ((lg * 32) ^ xo));             \
            f32x4 hi = *(const f32x4*)(base + ((lg * 32 + 16) ^ xo));        \
            fa[i] = pack8v(lo, hi);                                          \
        }                                                                    \
        _Pragma("unroll")                                                    \
        for (int j = 0; j < 4; ++j) {                                        \
            const int m = mh + 16 * j + l15;                                 \
            const char* base = (const char*)&lds[d][2048 + m * 32];          \
            const int xo = (m & 7) << 4;                                     \
            f32x4 lo = *(const f32x4*)(base + ((lg * 32) ^ xo));             \
            f32x4 hi = *(const f32x4*)(base + ((lg * 32 + 16) ^ xo));        \
            fb[j] = pack8v(lo, hi);                                          \
        }                                                                    \
        _Pragma("unroll")                                                    \
        for (int i = 0; i < 2; ++i)                                          \
            _Pragma("unroll")                                                \
            for (int j = 0; j < 4; ++j)                                      \
                acc[i][j] = __builtin_amdgcn_mfma_f32_16x16x32_bf16(fa[i], fb[j], acc[i][j], 0, 0, 0); \
    } while (0)

    STAGE(0, 0);
    __syncthreads();
    for (int ks = 0; ks < 16; ++ks) {
        const int d = ks & 1;
        if (ks < 15) STAGE(d ^ 1, ks + 1);   // overlap: DMA(t+1) || compute(t)
        SCOMP(d);
        __syncthreads();                     // drains own DMA + syncs buffers
    }
#undef STAGE
#undef SCOMP

    float* outp = part + (size_t)p * PART_ELEMS + c * 128;
#pragma unroll
    for (int i = 0; i < 2; ++i)
#pragma unroll
        for (int j = 0; j < 4; ++j) {
            float* o = outp + (size_t)(nh + i * 16 + lg * 4) * 16384 + mh + j * 16 + l15;
            o[0]     = acc[i][j][0];
            o[16384] = acc[i][j][1];
            o[32768] = acc[i][j][2];
            o[49152] = acc[i][j][3];
        }
}

// ---------------- Kernel 2: sum partials + softmax -> W (bf16) -----------
__global__ __launch_bounds__(256) void k_softmax(const float* __restrict__ part,
                                                 unsigned int* __restrict__ Wout) {
    const int t   = threadIdx.x;
    const int l   = t & 63;
    const int row = blockIdx.x * 4 + (t >> 6);   // row = n*128 + c

    const float* s = part + (size_t)row * 128 + 2 * l;
    float v0 = 0.f, v1 = 0.f;
#pragma unroll
    for (int p = 0; p < 4; ++p) {
        float2 v = *(const float2*)(s + (size_t)p * PART_ELEMS);
        v0 += v.x; v1 += v.y;
    }
    float mx = fmaxf(v0, v1);
#pragma unroll
    for (int d = 1; d < 64; d <<= 1) mx = fmaxf(mx, __shfl_xor(mx, d, 64));
    float e0 = __expf(v0 - mx), e1 = __expf(v1 - mx);
    float sm = e0 + e1;
#pragma unroll
    for (int d = 1; d < 64; d <<= 1) sm += __shfl_xor(sm, d, 64);
    const float inv = 1.0f / sm;
    Wout[(size_t)row * 64 + l] = f2bf_pk(e0 * inv, e1 * inv);
}

// ---------------- Kernel 3: combine (DMA-staged) --------------------------
// out[n] (128c x 2048f) = W[n](128x128) @ X[n](128m x 2048f)
// grid 1024 = (n:64) x (f-tile:16, 128f); block 256 (4 waves, 2c x 2f).
// W[n] preloaded to registers (16 x bf16x8 per lane). X staged per m-step:
// [32m][128f] fp32 (16 KB), double-buffered 32 KB; 16 DMA/step (4/wave).
// Swizzle: LDS[m][b] = G[m][b ^ (((m>>3)&3)<<5)]; read col f with same XOR.
__global__ __launch_bounds__(256, 2) void k_combine(const float* __restrict__ X,
                                                    const unsigned short* __restrict__ W,
                                                    float* __restrict__ out) {
    __shared__ float xt[2][4096];    // [buf][m(32)][f(128)]

    const int bx = blockIdx.x;
    const int n  = bx >> 4;
    const int fb = (bx & 15) * 128;
    const int t  = threadIdx.x;
    const int l  = t & 63;
    const int w  = t >> 6;
    const int l15 = l & 15;
    const int lg  = l >> 4;
    const int wc = (w >> 1) * 64;
    const int wf = (w & 1) * 64;

    // W fragments in registers: [c-tile][m-step], 16 x 16B coalesced loads
    bf16x8 wfr[4][4];
#pragma unroll
    for (int ct = 0; ct < 4; ++ct)
#pragma unroll
        for (int ms = 0; ms < 4; ++ms)
            wfr[ct][ms] = *(const bf16x8*)(W + ((size_t)n * 128 + wc + ct * 16 + l15) * 128
                                             + ms * 32 + lg * 8);

    // staging source: instr mi = w*4+q covers local rows m = mi*2 + (l>>5)
    const char* sg[4];
#pragma unroll
    for (int q = 0; q < 4; ++q) {
        const int mi = w * 4 + q;
        const int m  = mi * 2 + (l >> 5);                       // local m 0..31
        const int fswz = ((l & 31) * 16) ^ (((m >> 3) & 3) << 5);
        sg[q] = (const char*)(X + ((size_t)n * 128 + m) * 2048 + fb) + fswz;
    }

#define CSTAGE(d, ms) do {                                                   \
        _Pragma("unroll")                                                    \
        for (int q = 0; q < 4; ++q)                                          \
            gload_lds16(sg[q] + (size_t)(ms) * (32 * 2048 * 4),              \
                        &xt[d][(w * 4 + q) * 256]);                          \
    } while (0)

    f32x4 acc[4][4];
#pragma unroll
    for (int i = 0; i < 4; ++i)
#pragma unroll
        for (int j = 0; j < 4; ++j) acc[i][j] = (f32x4)0.0f;

#define CCOMP(d, ms) do {                                                    \
        _Pragma("unroll")                                                    \
        for (int jt = 0; jt < 4; ++jt) {                                     \
            const int fcb = ((wf + jt * 16 + l15) * 4) ^ (lg << 5);          \
            const char* base = (const char*)&xt[d][0] + (size_t)lg * 8 * 512 + fcb; \
            float v0 = *(const float*)(base + 0 * 512);                      \
            float v1 = *(const float*)(base + 1 * 512);                      \
            float v2 = *(const float*)(base + 2 * 512);                      \
            float v3 = *(const float*)(base + 3 * 512);                      \
            float v4 = *(const float*)(base + 4 * 512);                      \
            float v5 = *(const float*)(base + 5 * 512);                      \
            float v6 = *(const float*)(base + 6 * 512);                      \
            float v7 = *(const float*)(base + 7 * 512);                      \
            bf16x8 q8 = pack8s(v0, v1, v2, v3, v4, v5, v6, v7);              \
            _Pragma("unroll")                                                \
            for (int ct = 0; ct < 4; ++ct)                                   \
                acc[ct][jt] = __builtin_amdgcn_mfma_f32_16x16x32_bf16(wfr[ct][ms], q8, acc[ct][jt], 0, 0, 0); \
        }                                                                    \
    } while (0)

    CSTAGE(0, 0);
    __syncthreads();
#pragma unroll
    for (int ms = 0; ms < 4; ++ms) {         // unrolled: wfr[][ms] stays in regs
        const int d = ms & 1;
        if (ms < 3) CSTAGE(d ^ 1, ms + 1);
        CCOMP(d, ms);
        __syncthreads();
    }
#undef CSTAGE
#undef CCOMP

#pragma unroll
    for (int ct = 0; ct < 4; ++ct)
#pragma unroll
        for (int jt = 0; jt < 4; ++jt) {
            float* o = out + ((size_t)n * 128 + wc + ct * 16 + lg * 4) * 2048
                           + fb + wf + jt * 16 + l15;
            o[0]        = acc[ct][jt][0];
            o[2048]     = acc[ct][jt][1];
            o[2 * 2048] = acc[ct][jt][2];
            o[3 * 2048] = acc[ct][jt][3];
        }
}

extern "C" void kernel_launch(void* const* d_in, const int* in_sizes, int n_in,
                              void* d_out, int out_size, void* d_ws, size_t ws_size,
                              hipStream_t stream) {
    const float* X = (const float*)d_in[0];   // [64,128,2048]
    const float* A = (const float*)d_in[1];   // [128,128,2048]
    float* out = (float*)d_out;               // [64,128,2048]

    float* part = (float*)d_ws;                                        // 16 MiB
    unsigned short* W = (unsigned short*)((char*)d_ws + WOFF_BYTES);   // 2 MiB bf16

    k_scores<<<dim3(512), dim3(256), 0, stream>>>(X, A, part);
    k_softmax<<<dim3(2048), dim3(256), 0, stream>>>(part, (unsigned int*)W);
    k_combine<<<dim3(1024), dim3(256), 0, stream>>>(X, W, out);
}